// Round 3
// baseline (191.278 us; speedup 1.0000x reference)
//
#include <hip/hip_runtime.h>

// HardMoE classifier: B=131072, D=768, E=6, L=2.
// R3: LDS-issue bound fixed — weights in VGPRs (gate f32, experts bf16-packed),
//     x via wave-private LDS staging (linear b128 reads), DPP wave64 reduction.
//     No __syncthreads anywhere; counted vmcnt pipeline per wave.

#define BB 131072
#define DD 768
#define ROWS_PER_WAVE 64
#define ROWS_PER_TILE 2
#define NT (ROWS_PER_WAVE / ROWS_PER_TILE)   // 32 tiles
#define WPB 8                                 // waves per block
#define NTHREADS (WPB * 64)

#define GLOAD_LDS16(gsrc, ldst)                                                \
  __builtin_amdgcn_global_load_lds(                                            \
      (const __attribute__((address_space(1))) void*)(gsrc),                   \
      (__attribute__((address_space(3))) void*)(ldst), 16, 0, 0)

__device__ __forceinline__ float lo16f(unsigned u) {
  return __builtin_bit_cast(float, u << 16);
}
__device__ __forceinline__ float hi16f(unsigned u) {
  return __builtin_bit_cast(float, u & 0xffff0000u);
}
__device__ __forceinline__ unsigned bf16_rne(float x) {
  unsigned u = __builtin_bit_cast(unsigned, x);
  return (u + 0x7fffu + ((u >> 16) & 1u)) >> 16;
}
__device__ __forceinline__ unsigned pack2(float a, float b) {
  return bf16_rne(a) | (bf16_rne(b) << 16);
}

// LLVM-canonical wave64 sum; full sum valid in lanes 48..63.
__device__ __forceinline__ float wave_red_sum(float v) {
#define STEP(CTRL, RM)                                                         \
  v += __builtin_bit_cast(float, __builtin_amdgcn_update_dpp(                  \
           0, __builtin_bit_cast(int, v), CTRL, RM, 0xf, true));
  STEP(0xB1, 0xf)   // quad_perm [1,0,3,2]  (xor 1)
  STEP(0x4E, 0xf)   // quad_perm [2,3,0,1]  (xor 2)
  STEP(0x141, 0xf)  // row_half_mirror      (xor 4)
  STEP(0x140, 0xf)  // row_mirror           (xor 8)
  STEP(0x142, 0xa)  // row_bcast15 -> rows 1,3
  STEP(0x143, 0xc)  // row_bcast31 -> rows 2,3
#undef STEP
  return v;
}

__global__ __launch_bounds__(NTHREADS, 2)
void HardMoE_kernel(const float* __restrict__ X,   // [B][768]
                    const float* __restrict__ gw,  // [6][768]
                    const float* __restrict__ gb,  // [6]
                    const float* __restrict__ ew,  // [6][768][2]
                    const float* __restrict__ eb,  // [6][2]
                    float* __restrict__ out)       // [B][2]
{
  // wave-private double-buffered x tiles: 8 waves x 2 bufs x (2 rows x 768) = 96 KB
  __shared__ float lds[WPB][2][ROWS_PER_TILE * DD];

  const int tid  = threadIdx.x;
  const int lane = tid & 63;
  const int w    = tid >> 6;
  const size_t row0 = ((size_t)blockIdx.x * WPB + w) * ROWS_PER_WAVE;
  const int dbase = 4 * lane;   // lane's d-slice: {dbase + 256k + 0..3}

  // ---- weights -> VGPRs (one-time, coalesced) ----
  float4 wg[6][3];   // gate, f32
  uint4  we[6][3];   // experts, bf16-packed: .x=(w[d][0],w[d][1]) .y=d+1 .z=d+2 .w=d+3
#pragma unroll
  for (int j = 0; j < 6; ++j)
#pragma unroll
    for (int k = 0; k < 3; ++k)
      wg[j][k] = *(const float4*)(gw + j * DD + dbase + 256 * k);
#pragma unroll
  for (int e = 0; e < 6; ++e)
#pragma unroll
    for (int k = 0; k < 3; ++k) {
      const float* p = ew + 2 * (e * DD + dbase + 256 * k);
      const float4 a = *(const float4*)(p);      // d,d+1 (l interleaved)
      const float4 b = *(const float4*)(p + 4);  // d+2,d+3
      we[e][k] = make_uint4(pack2(a.x, a.y), pack2(a.z, a.w),
                            pack2(b.x, b.y), pack2(b.z, b.w));
    }
  float gbv[6], ebv[12];
#pragma unroll
  for (int j = 0; j < 6; ++j) gbv[j] = gb[j];     // uniform -> s_load
#pragma unroll
  for (int i = 0; i < 12; ++i) ebv[i] = eb[i];
  // pin weight loads BEFORE staging so vmcnt counts below are exact
  asm volatile("" ::: "memory");

  auto stage = [&](int buf, int t) {
    const float* src = X + (row0 + (size_t)t * ROWS_PER_TILE) * DD;
    float* dst = &lds[w][buf][0];
#pragma unroll
    for (int i = 0; i < 6; ++i)
      GLOAD_LDS16(src + i * 256 + 4 * lane, dst + i * 256);
  };

  stage(0, 0);

  for (int t = 0; t < NT; ++t) {
    if (t + 1 < NT) stage((t + 1) & 1, t + 1);
    // queue (oldest->newest) at this point:
    //   t==0:    [s0(6), s1(6)]                 -> keep 6  (drain s0)
    //   0<t<31:  [s(t)(6), st(t-1)(2), s(t+1)(6)] -> keep 8 (drain s(t))
    //   t==31:   [s31(6), st30(2)]              -> keep 2  (drain s31)
    if (t == 0)            asm volatile("s_waitcnt vmcnt(6)" ::: "memory");
    else if (t < NT - 1)   asm volatile("s_waitcnt vmcnt(8)" ::: "memory");
    else                   asm volatile("s_waitcnt vmcnt(2)" ::: "memory");

    const float* bufp = &lds[w][t & 1][0];
#pragma unroll 1
    for (int r = 0; r < ROWS_PER_TILE; ++r) {
      const float* xr = bufp + r * DD + dbase;
      float acc[18];
#pragma unroll
      for (int j = 0; j < 18; ++j) acc[j] = 0.f;
#pragma unroll
      for (int k = 0; k < 3; ++k) {
        const float4 xv = *(const float4*)(xr + 256 * k);   // linear b128
#pragma unroll
        for (int j = 0; j < 6; ++j)
          acc[j] += xv.x * wg[j][k].x + xv.y * wg[j][k].y +
                    xv.z * wg[j][k].z + xv.w * wg[j][k].w;
#pragma unroll
        for (int e = 0; e < 6; ++e) {
          const uint4 p = we[e][k];
          acc[6 + 2 * e] += xv.x * lo16f(p.x) + xv.y * lo16f(p.y) +
                            xv.z * lo16f(p.z) + xv.w * lo16f(p.w);
          acc[7 + 2 * e] += xv.x * hi16f(p.x) + xv.y * hi16f(p.y) +
                            xv.z * hi16f(p.z) + xv.w * hi16f(p.w);
        }
      }
      // gate reduce + argmax (valid in lanes 48..63; lane 63 is authoritative)
      float g[6];
#pragma unroll
      for (int j = 0; j < 6; ++j) g[j] = wave_red_sum(acc[j]) + gbv[j];
      int best = 0; float bv = g[0];
#pragma unroll
      for (int j = 1; j < 6; ++j) { if (g[j] > bv) { bv = g[j]; best = j; } }
      best = __builtin_amdgcn_readlane(best, 63);   // broadcast to all lanes
      float p0 = acc[6], p1 = acc[7], b0 = ebv[0], b1 = ebv[1];
#pragma unroll
      for (int e = 1; e < 6; ++e) {
        const bool s = (best == e);
        p0 = s ? acc[6 + 2 * e] : p0;  p1 = s ? acc[7 + 2 * e] : p1;
        b0 = s ? ebv[2 * e] : b0;      b1 = s ? ebv[2 * e + 1] : b1;
      }
      const float o0 = wave_red_sum(p0) + b0;
      const float o1 = wave_red_sum(p1) + b1;
      if (lane == 63)
        ((float2*)out)[row0 + (size_t)t * ROWS_PER_TILE + r] = make_float2(o0, o1);
    }
  }
}

extern "C" void kernel_launch(void* const* d_in, const int* in_sizes, int n_in,
                              void* d_out, int out_size, void* d_ws, size_t ws_size,
                              hipStream_t stream) {
  (void)in_sizes; (void)n_in; (void)d_ws; (void)ws_size; (void)out_size;
  const float* X  = (const float*)d_in[0];
  const float* gw = (const float*)d_in[1];
  const float* gb = (const float*)d_in[2];
  const float* ew = (const float*)d_in[3];
  const float* eb = (const float*)d_in[4];
  float* out = (float*)d_out;
  const int nblocks = BB / (WPB * ROWS_PER_WAVE);   // 256
  HardMoE_kernel<<<nblocks, NTHREADS, 0, stream>>>(X, gw, gb, ew, eb, out);
}

// Round 4
// 155.052 us; speedup vs baseline: 1.2336x; 1.2336x over previous
//
#include <hip/hip_runtime.h>

// HardMoE classifier: B=131072, D=768, E=6, L=2.
// Per row: 18 dots of length 768 (6 gate f32-exact + 12 expert), argmax-select.
// Memory-bound: 403 MB X read -> ~64us floor @ 6.3 TB/s.
// R4: thread-per-row (R2 structure) with the LDS issue count cut 19->7 per chunk:
//     gate weights via scalar-promoted s_loads (uniform addr, sL1-resident),
//     expert weights bf16-packed in LDS (1 b128 broadcast per expert per 4d).
//     2 blocks/CU (8 waves), wave-private staging strips, zero main-loop barriers,
//     counted vmcnt(4) double-buffer pipeline.

#define BB 131072
#define DD 768
#define ROWS 256            // threads per block = rows per block
#define TILE_D 16           // floats per staged d-tile
#define NT (DD / TILE_D)    // 24 tiles
#define NPAIR (6 * 768)     // expert (d -> label-pair) count

#define GLOAD_LDS16(gsrc, ldst)                                                \
  __builtin_amdgcn_global_load_lds(                                            \
      (const __attribute__((address_space(1))) void*)(gsrc),                   \
      (__attribute__((address_space(3))) void*)(ldst), 16, 0, 0)

__device__ __forceinline__ float lo16f(unsigned u) {
  return __builtin_bit_cast(float, u << 16);
}
__device__ __forceinline__ float hi16f(unsigned u) {
  return __builtin_bit_cast(float, u & 0xffff0000u);
}
__device__ __forceinline__ unsigned bf16_rne(float x) {
  unsigned u = __builtin_bit_cast(unsigned, x);
  return (u + 0x7fffu + ((u >> 16) & 1u)) >> 16;
}

__global__ __launch_bounds__(ROWS, 2)
void HardMoE_kernel(const float* __restrict__ X,   // [B][768]
                    const float* __restrict__ gw,  // [6][768]
                    const float* __restrict__ gb,  // [6]
                    const float* __restrict__ ew,  // [6][768][2]
                    const float* __restrict__ eb,  // [6][2]
                    float* __restrict__ out)       // [B][2]
{
  // x tiles: [buf][row][slot] f32, 16B-slot XOR swizzle slot^(row&3): 32 KB
  __shared__ float    xlds[2][ROWS * TILE_D];
  // expert weights bf16 pair (w[e][d][0], w[e][d][1]) per uint: 18 KB
  __shared__ unsigned ewlds[NPAIR];

  const int tid  = threadIdx.x;
  const int lane = tid & 63;
  const int w    = tid >> 6;                  // wave 0..3
  const int row0 = blockIdx.x * ROWS;

  // ---- one-time: pack expert weights f32x2 -> bf16 pair (coalesced) ----
  for (int i = tid; i < NPAIR; i += ROWS) {
    const float2 p = ((const float2*)ew)[i];
    ewlds[i] = bf16_rne(p.x) | (bf16_rne(p.y) << 16);
  }

  // wave-private staging: wave w owns rows [64w, 64w+64); 4 x 1KB insts/tile.
  // pre-swizzled GLOBAL source + linear LDS dest (rule 21).
  auto stage = [&](int buf, int tile) {
#pragma unroll
    for (int i = 0; i < 4; ++i) {
      const int base_r = w * 64 + i * 16;                 // wave-uniform
      const int r      = base_r + (lane >> 2);
      const int sg     = (lane & 3) ^ ((lane >> 2) & 3);  // swizzled col-group
      GLOAD_LDS16(X + (size_t)(row0 + r) * DD + tile * TILE_D + sg * 4,
                  &xlds[buf][base_r * TILE_D]);
    }
  };

  stage(0, 0);
  stage(1, 1);
  __syncthreads();   // ewlds visible to all waves (prologue-only barrier)

  float acc[18];     // 0..5 gate (f32-exact), 6..17 expert (e*2+l)
#pragma unroll
  for (int j = 0; j < 18; ++j) acc[j] = 0.f;

  for (int t = 0; t < NT; ++t) {
    // own strip's tile-t loads done; keep next tile's 4 in flight
    if (t + 1 < NT) asm volatile("s_waitcnt vmcnt(4)" ::: "memory");
    else            asm volatile("s_waitcnt vmcnt(0)" ::: "memory");

    const float* xb = &xlds[t & 1][tid * TILE_D];
    const int d0 = t * TILE_D;
#pragma unroll
    for (int g = 0; g < 4; ++g) {
      const float4 xv = *(const float4*)(xb + (((g ^ tid) & 3) << 2));  // un-swizzle
      const int d = d0 + g * 4;
#pragma unroll
      for (int j = 0; j < 6; ++j) {                 // gate: uniform -> s_load_dwordx4
        const float4 wv = *(const float4*)(gw + j * DD + d);
        acc[j] += xv.x * wv.x + xv.y * wv.y + xv.z * wv.z + xv.w * wv.w;
      }
#pragma unroll
      for (int e = 0; e < 6; ++e) {                 // experts: 1 b128 broadcast each
        const uint4 wp = *(const uint4*)(&ewlds[e * DD + d]);
        acc[6 + 2 * e] += xv.x * lo16f(wp.x) + xv.y * lo16f(wp.y) +
                          xv.z * lo16f(wp.z) + xv.w * lo16f(wp.w);
        acc[7 + 2 * e] += xv.x * hi16f(wp.x) + xv.y * hi16f(wp.y) +
                          xv.z * hi16f(wp.z) + xv.w * hi16f(wp.w);
      }
    }
    // depth-2 prefetch AFTER this tile's reads (same buffer t&1 reused for t+2)
    if (t + 2 < NT) stage(t & 1, t + 2);
  }

  // ---- epilogue: argmax (first-max rule = jnp.argmax) + select + store ----
  float gbv[6], ebv[12];
#pragma unroll
  for (int j = 0; j < 6; ++j) gbv[j] = gb[j];       // uniform -> s_load
#pragma unroll
  for (int i = 0; i < 12; ++i) ebv[i] = eb[i];

  int   best = 0;
  float bv   = acc[0] + gbv[0];
#pragma unroll
  for (int j = 1; j < 6; ++j) {
    const float v = acc[j] + gbv[j];
    if (v > bv) { bv = v; best = j; }
  }
  float o0 = acc[6] + ebv[0], o1 = acc[7] + ebv[1];
#pragma unroll
  for (int e = 1; e < 6; ++e) {
    const bool s = (best == e);
    o0 = s ? acc[6 + 2 * e] + ebv[2 * e]     : o0;
    o1 = s ? acc[7 + 2 * e] + ebv[2 * e + 1] : o1;
  }

  ((float2*)out)[row0 + tid] = make_float2(o0, o1);
}

extern "C" void kernel_launch(void* const* d_in, const int* in_sizes, int n_in,
                              void* d_out, int out_size, void* d_ws, size_t ws_size,
                              hipStream_t stream) {
  (void)in_sizes; (void)n_in; (void)d_ws; (void)ws_size; (void)out_size;
  const float* X  = (const float*)d_in[0];
  const float* gw = (const float*)d_in[1];
  const float* gb = (const float*)d_in[2];
  const float* ew = (const float*)d_in[3];
  const float* eb = (const float*)d_in[4];
  float* out = (float*)d_out;
  HardMoE_kernel<<<BB / ROWS, ROWS, 0, stream>>>(X, gw, gb, ew, eb, out);
}